// Round 6
// baseline (919.645 us; speedup 1.0000x reference)
//
#include <hip/hip_runtime.h>
#include <math.h>

#define HIDDEN 256
#define NEG 1024
#define NBATCH 256
#define GAMMA_F 12.0f
#define LDB 264      // B row stride in bf16 (264*2=528B = 33*16 -> 16B aligned, banks 2-way/free)
#define NBLK 256     // 1 block/CU, 512 threads, 8 waves; wave owns 8 tiles of 16 rows

typedef short v8s __attribute__((ext_vector_type(8)));
typedef float v4f __attribute__((ext_vector_type(4)));
typedef unsigned int u32;

// fp32 -> bf16 round-to-nearest-even (scalar, prep kernel)
__device__ __forceinline__ short f2bf(float x) {
    u32 u = __float_as_uint(x);
    u = (u + 0x7fffu + ((u >> 16) & 1u)) >> 16;
    return (short)u;
}

// pack 8 fp32 -> v8s bf16 (round-half-up + v_perm byte-pack)
__device__ __forceinline__ u32 rhu(float f) { return __float_as_uint(f) + 0x8000u; }
__device__ __forceinline__ v8s pack8(const float4& x0, const float4& x1) {
    int4 fr;
    fr.x = __builtin_amdgcn_perm(rhu(x0.y), rhu(x0.x), 0x07060302u);
    fr.y = __builtin_amdgcn_perm(rhu(x0.w), rhu(x0.z), 0x07060302u);
    fr.z = __builtin_amdgcn_perm(rhu(x1.y), rhu(x1.x), 0x07060302u);
    fr.w = __builtin_amdgcn_perm(rhu(x1.w), rhu(x1.z), 0x07060302u);
    return __builtin_bit_cast(v8s, fr);
}

// One block per batch row b: h_n[b,:], rel_part[b,:] in fp32; convert W1 row b -> bf16.
__global__ __launch_bounds__(256) void prep_kernel(
    const int* __restrict__ head, const int* __restrict__ relation,
    const float* __restrict__ entity_emb, const float* __restrict__ relation_emb,
    const float* __restrict__ W_fc, const float* __restrict__ b_fc,
    short* __restrict__ W1bf, float* __restrict__ h_n, float* __restrict__ rel_part)
{
    const int b = blockIdx.x;
    const int t = threadIdx.x;

    W1bf[b * HIDDEN + t] = f2bf(W_fc[(size_t)b * 2 * HIDDEN + t]);

    __shared__ float xh[2 * HIDDEN];
    __shared__ float xt[HIDDEN];
    __shared__ float red[256];

    const int hidx = head[b];
    const int r = relation[b];
    xh[t]          = entity_emb[(size_t)hidx * HIDDEN + t];
    xh[HIDDEN + t] = relation_emb[(size_t)r * 2 * HIDDEN + t];
    xt[t]          = relation_emb[(size_t)r * 2 * HIDDEN + HIDDEN + t];
    __syncthreads();

    const float4* wrow = reinterpret_cast<const float4*>(W_fc + (size_t)t * 2 * HIDDEN);
    float hf = b_fc[t];
    float rp = b_fc[t];
    #pragma unroll 4
    for (int kk = 0; kk < HIDDEN / 4; ++kk) {
        float4 w = wrow[kk];
        hf += xh[4*kk+0]*w.x + xh[4*kk+1]*w.y + xh[4*kk+2]*w.z + xh[4*kk+3]*w.w;
    }
    #pragma unroll 4
    for (int kk = 0; kk < HIDDEN / 4; ++kk) {
        float4 w = wrow[HIDDEN/4 + kk];
        hf += xh[HIDDEN+4*kk+0]*w.x + xh[HIDDEN+4*kk+1]*w.y + xh[HIDDEN+4*kk+2]*w.z + xh[HIDDEN+4*kk+3]*w.w;
        rp += xt[4*kk+0]*w.x + xt[4*kk+1]*w.y + xt[4*kk+2]*w.z + xt[4*kk+3]*w.w;
    }
    rel_part[b * HIDDEN + t] = rp;

    red[t] = hf * hf;
    __syncthreads();
    for (int s = 128; s > 0; s >>= 1) {
        if (t < s) red[t] += red[t + s];
        __syncthreads();
    }
    const float norm = sqrtf(red[0]);
    h_n[b * HIDDEN + t] = hf / fmaxf(norm, 1e-12f);
}

// R6 restructure: B (256x256 bf16) staged ONCE into LDS (padded stride 264);
// A loaded directly global->registers in MFMA fragment layout with a
// slot-rotating 1-tile-deep software pipeline (constant vmcnt depth ~14,
// never drains). Zero barriers after the single B-staging sync; epilogue is
// pure intra-wave shfl. 512 thr/block, 1 block/CU (LDS 135 KB), 2 waves/SIMD.
__global__ __launch_bounds__(512, 2) void score_kernel(
    const int* __restrict__ tail, const float* __restrict__ entity_emb,
    const short* __restrict__ W1bf, const float* __restrict__ h_n,
    const float* __restrict__ rel_part, float* __restrict__ out)
{
    __shared__ __align__(16) short Bs[HIDDEN * LDB];   // 135168 B

    const int t = threadIdx.x;        // 0..511
    const int w = t >> 6;             // wave 0..7
    const int c = t & 15;
    const int g = (t >> 4) & 3;

    // ---- stage B once: W1bf row n -> Bs row n (padded) ----
    {
        const int n = t >> 1;
        const int h = (t & 1) * 128;
        const short* src = W1bf + (size_t)n * HIDDEN + h;
        short* dst = Bs + n * LDB + h;
        #pragma unroll
        for (int i = 0; i < 16; ++i)
            *reinterpret_cast<v8s*>(dst + i * 8) = *reinterpret_cast<const v8s*>(src + i * 8);
    }

    const int m0w = (blockIdx.x * 8 + w) * 128;   // wave's 128 rows (8 tiles x 16)
    const int b   = m0w >> 10;                    // constant per wave

    // per-lane epilogue constants: col n = nt*16 + c
    float rlv[16], hnv[16];
    #pragma unroll
    for (int nt = 0; nt < 16; ++nt) {
        rlv[nt] = rel_part[b * HIDDEN + nt * 16 + c];
        hnv[nt] = h_n[b * HIDDEN + nt * 16 + c];
    }

    // tail rows for all 8 tiles (lane c selects the row within each 16-row tile)
    int rows[8];
    #pragma unroll
    for (int j = 0; j < 8; ++j) rows[j] = tail[m0w + j * 16 + c];

    // prefetch tile 0's A fragments: lane(g,c) reads row rows[0], floats [kt*32+g*8, +8)
    float4 ld[16];
    {
        const float* p = entity_emb + (size_t)rows[0] * HIDDEN + g * 8;
        #pragma unroll
        for (int kt = 0; kt < 8; ++kt) {
            ld[2 * kt]     = *reinterpret_cast<const float4*>(p + kt * 32);
            ld[2 * kt + 1] = *reinterpret_cast<const float4*>(p + kt * 32 + 4);
        }
    }

    __syncthreads();   // Bs visible; the only block-wide barrier

    #pragma unroll 1
    for (int j = 0; j < 8; ++j) {
        const float* pn = entity_emb + (size_t)rows[(j + 1) & 7] * HIDDEN + g * 8;

        v4f acc[16];
        #pragma unroll
        for (int nt = 0; nt < 16; ++nt) acc[nt] = v4f{0.f, 0.f, 0.f, 0.f};

        #pragma unroll
        for (int kt = 0; kt < 8; ++kt) {
            float4 x0 = ld[2 * kt], x1 = ld[2 * kt + 1];   // consume (vmcnt ~14 wait)
            if (j != 7) {                                   // reissue slot for tile j+1
                ld[2 * kt]     = *reinterpret_cast<const float4*>(pn + kt * 32);
                ld[2 * kt + 1] = *reinterpret_cast<const float4*>(pn + kt * 32 + 4);
            }
            v8s a = pack8(x0, x1);
            #pragma unroll
            for (int nt = 0; nt < 16; ++nt) {
                v8s bf = *reinterpret_cast<const v8s*>(
                    Bs + (nt * 16 + c) * LDB + kt * 32 + g * 8);
                acc[nt] = __builtin_amdgcn_mfma_f32_16x16x32_bf16(a, bf, acc[nt], 0, 0, 0);
            }
        }

        // ---- epilogue (intra-wave): row m = g*4 + r, col = nt*16 + c ----
        float sc4[4];
        {
            float ssq[4] = {0.f, 0.f, 0.f, 0.f};
            #pragma unroll
            for (int nt = 0; nt < 16; ++nt) {
                #pragma unroll
                for (int r = 0; r < 4; ++r) {
                    float tf = acc[nt][r] + rlv[nt];
                    acc[nt][r] = tf;
                    ssq[r] += tf * tf;
                }
            }
            #pragma unroll
            for (int mask = 1; mask < 16; mask <<= 1) {
                #pragma unroll
                for (int r = 0; r < 4; ++r) ssq[r] += __shfl_xor(ssq[r], mask);
            }
            #pragma unroll
            for (int r = 0; r < 4; ++r) {
                float rn = 1.f / fmaxf(sqrtf(ssq[r]), 1e-12f);
                float s = 0.f;
                #pragma unroll
                for (int nt = 0; nt < 16; ++nt)
                    s += fabsf(hnv[nt] - acc[nt][r] * rn);
                sc4[r] = s;
            }
            #pragma unroll
            for (int mask = 1; mask < 16; mask <<= 1) {
                #pragma unroll
                for (int r = 0; r < 4; ++r) sc4[r] += __shfl_xor(sc4[r], mask);
            }
        }
        if (c == 0) {
            float4 o = make_float4(GAMMA_F - sc4[0], GAMMA_F - sc4[1],
                                   GAMMA_F - sc4[2], GAMMA_F - sc4[3]);
            *reinterpret_cast<float4*>(out + m0w + j * 16 + g * 4) = o;
        }
    }
}

extern "C" void kernel_launch(void* const* d_in, const int* in_sizes, int n_in,
                              void* d_out, int out_size, void* d_ws, size_t ws_size,
                              hipStream_t stream)
{
    const int*   head         = (const int*)d_in[0];
    const int*   tail         = (const int*)d_in[1];
    const int*   relation     = (const int*)d_in[2];
    const float* entity_emb   = (const float*)d_in[3];
    const float* relation_emb = (const float*)d_in[4];
    const float* W_fc         = (const float*)d_in[5];
    const float* b_fc         = (const float*)d_in[6];
    float* out = (float*)d_out;

    // ws layout: W1 bf16 (128 KiB) | h_n f32 (256 KiB) | rel_part f32 (256 KiB)
    short* W1bf     = (short*)d_ws;
    float* h_n      = (float*)((char*)d_ws + 131072);
    float* rel_part = (float*)((char*)d_ws + 131072 + 262144);

    prep_kernel<<<NBATCH, 256, 0, stream>>>(head, relation, entity_emb, relation_emb,
                                            W_fc, b_fc, W1bf, h_n, rel_part);
    score_kernel<<<NBLK, 512, 0, stream>>>(tail, entity_emb, W1bf,
                                           h_n, rel_part, out);
}